// Round 1
// baseline (533.504 us; speedup 1.0000x reference)
//
#include <hip/hip_runtime.h>
#include <math.h>

// Problem constants (from reference)
#define BB 4
#define NN 1000
#define TT 12
#define DD 64
#define HIDN 128
#define EFN 64
#define EE 64000
#define BN (BB*NN)        // 4000 segments
#define ROWS (BN*TT)      // 48000 node-time rows
#define TD (TT*DD)        // 768 elements per edge/node row-block
#define STEPF 0.1f
#define MAXSEG 27         // LDS-resident edges per sender segment (3 blocks/CU)

typedef _Float16 f16x8 __attribute__((ext_vector_type(8)));   // 8 x f16 (4 VGPR)
typedef float f32x4 __attribute__((ext_vector_type(4)));      // MFMA acc

__device__ __forceinline__ unsigned short f2h(float x) {
    _Float16 h = (_Float16)x;                 // v_cvt_f16_f32 (RNE)
    return __builtin_bit_cast(unsigned short, h);
}
__device__ __forceinline__ float h2f(unsigned short u) {
    return (float)__builtin_bit_cast(_Float16, u);
}

// ---------------------------------------------------------------------------
// CSR build helpers
// ---------------------------------------------------------------------------
__global__ __launch_bounds__(256) void k_zero(int* __restrict__ p, int n) {
    int i = blockIdx.x * 256 + threadIdx.x;
    if (i < n) p[i] = 0;
}

__global__ __launch_bounds__(256) void k_count(const int* __restrict__ bi,
                                               const int* __restrict__ si,
                                               const int* __restrict__ ri,
                                               int* __restrict__ cnt_s,
                                               int* __restrict__ cnt_r) {
    int e = blockIdx.x * 256 + threadIdx.x;
    if (e < EE) {
        int b = bi[e];
        atomicAdd(&cnt_s[b * NN + si[e]], 1);
        atomicAdd(&cnt_r[b * NN + ri[e]], 1);
    }
}

__global__ __launch_bounds__(256) void k_scan(const int* __restrict__ cnt_s,
                                              const int* __restrict__ cnt_r,
                                              int* __restrict__ rp_s, int* __restrict__ rp_r,
                                              int* __restrict__ cur_s, int* __restrict__ cur_r) {
    const int* cnt = blockIdx.x ? cnt_r : cnt_s;
    int* rp  = blockIdx.x ? rp_r  : rp_s;
    int* cur = blockIdx.x ? cur_r : cur_s;
    __shared__ int part[256];
    int tid = threadIdx.x;
    const int chunk = 16;
    int bgn = tid * chunk;
    int end = min(bgn + chunk, BN);
    int s = 0;
    for (int i = bgn; i < end; ++i) s += cnt[i];
    part[tid] = s;
    __syncthreads();
    for (int off = 1; off < 256; off <<= 1) {
        int v = part[tid];
        if (tid >= off) v += part[tid - off];
        __syncthreads();
        part[tid] = v;
        __syncthreads();
    }
    int run = tid ? part[tid - 1] : 0;
    for (int i = bgn; i < end; ++i) { rp[i] = run; cur[i] = run; run += cnt[i]; }
    if (tid == 255) rp[BN] = part[255];
}

__global__ __launch_bounds__(256) void k_fill(const int* __restrict__ bi,
                                              const int* __restrict__ si,
                                              const int* __restrict__ ri,
                                              int* __restrict__ cur_s, int* __restrict__ cur_r,
                                              int* __restrict__ el_s, int* __restrict__ el_r) {
    int e = blockIdx.x * 256 + threadIdx.x;
    if (e < EE) {
        int b = bi[e];
        int ps = atomicAdd(&cur_s[b * NN + si[e]], 1);
        el_s[ps] = e;
        int pr = atomicAdd(&cur_r[b * NN + ri[e]], 1);
        el_r[pr] = e;
    }
}

// ---------------------------------------------------------------------------
// Weight prep: repack A3_w [128,64] and A4_w [64,64] into f16 MFMA B-fragment
// order for 16x16x32: frag[kt][nt][lane][j] = W[kt*32 + (lane>>4)*8 + j][nt*16 + (lane&15)]
// ---------------------------------------------------------------------------
__global__ __launch_bounds__(256) void k_prep_w(const float* __restrict__ A3_w,
                                                const float* __restrict__ A4_w,
                                                unsigned short* __restrict__ W3f,
                                                unsigned short* __restrict__ W4f) {
    int i = blockIdx.x * 256 + threadIdx.x;    // 0 .. 12287
    if (i < 8192) {
        int j = i & 7, lane = (i >> 3) & 63, nt = (i >> 9) & 3, kt = i >> 11;
        int k = kt * 32 + (lane >> 4) * 8 + j;
        int n = nt * 16 + (lane & 15);
        W3f[i] = f2h(A3_w[k * 64 + n]);
    } else if (i < 12288) {
        int ii = i - 8192;
        int j = ii & 7, lane = (ii >> 3) & 63, nt = (ii >> 9) & 3, kt = ii >> 11;
        int k = kt * 32 + (lane >> 4) * 8 + j;
        int n = nt * 16 + (lane & 15);
        W4f[ii] = f2h(A4_w[k * 64 + n]);
    }
}

// ---------------------------------------------------------------------------
// K1: node projections Q1 = x@A1_w + A1_b, Q2 = x@A2_w + A2_b -> f16
// ---------------------------------------------------------------------------
__global__ __launch_bounds__(256) void k_node_proj(const float* __restrict__ x,
                                                   const float* __restrict__ A1_w,
                                                   const float* __restrict__ A1_b,
                                                   const float* __restrict__ A2_w,
                                                   const float* __restrict__ A2_b,
                                                   unsigned short* __restrict__ Q1,
                                                   unsigned short* __restrict__ Q2) {
    __shared__ float xs[16][64];
    int tid = threadIdx.x;
    int row0 = blockIdx.x * 16;
    {
        int i = tid * 4;
        int r = i >> 6, k = i & 63;
        *(float4*)&xs[r][k] = *(const float4*)&x[(size_t)(row0 + r) * 64 + k];
    }
    __syncthreads();
    int h = tid & 127;
    int w = tid >> 7;
    const float* W = w ? A2_w : A1_w;
    float bias = w ? A2_b[h] : A1_b[h];
    float acc[16];
#pragma unroll
    for (int r = 0; r < 16; ++r) acc[r] = 0.f;
    for (int k = 0; k < 64; ++k) {
        float wv = W[k * 128 + h];
#pragma unroll
        for (int r = 0; r < 16; ++r) acc[r] += xs[r][k] * wv;
    }
    unsigned short* Qo = w ? Q2 : Q1;
    for (int r = 0; r < 16; ++r) Qo[(size_t)(row0 + r) * 128 + h] = f2h(acc[r] + bias);
}

// ---------------------------------------------------------------------------
// K2 (f16 MFMA + fused segment softmax): one workgroup per sender segment.
// G = relu(Q1s+Q2r) - relu(Q1r+Q2s) built with packed v_pk_add/max_f16 (no
// scalar unpack/repack). Stage-1 H round-trips LDS as f16: b16 stores,
// ds_read_b128 yields the A-fragment directly (zero converts on read).
// Sender node index == blockIdx (seg = b*N + s), so no bi/si loads.
// LDS 53,280 B -> 3 blocks/CU.
// ---------------------------------------------------------------------------
__global__ __launch_bounds__(256, 3) void k_edge_seg(const unsigned short* __restrict__ Q1,
                                                     const unsigned short* __restrict__ Q2,
                                                     const int* __restrict__ ri,
                                                     const int* __restrict__ rp_s,
                                                     const int* __restrict__ el_s,
                                                     const unsigned short* __restrict__ W3f,
                                                     const unsigned short* __restrict__ W4f,
                                                     const float* __restrict__ A4_b,
                                                     float* __restrict__ v) {
    __shared__ unsigned short Vseg[MAXSEG][12][68];   // 44064 B (t-pitch 68: quads hit disjoint banks)
    __shared__ __align__(16) _Float16 Hs[4][16][72];  // 9216 B (pitch 72: 16B-aligned b128 rows)

    int seg = blockIdx.x;
    int beg = rp_s[seg], end = rp_s[seg + 1];
    int S = end - beg;
    if (S == 0) return;

    int tid  = threadIdx.x;
    int lane = tid & 63;
    int wv   = tid >> 6;
    int quad = lane >> 4;
    int m    = lane & 15;
    int kbase = quad * 8;
    int b    = seg / NN;           // batch id (seg = b*NN + sender)

    // Register-resident weight fragments (f16)
    f16x8 w3[4][4], w4[2][4];
#pragma unroll
    for (int kt = 0; kt < 4; ++kt)
#pragma unroll
        for (int nt = 0; nt < 4; ++nt)
            w3[kt][nt] = *(const f16x8*)&W3f[((kt * 4 + nt) * 64 + lane) * 8];
#pragma unroll
    for (int kt = 0; kt < 2; ++kt)
#pragma unroll
        for (int nt = 0; nt < 4; ++nt)
            w4[kt][nt] = *(const f16x8*)&W4f[((kt * 4 + nt) * 64 + lane) * 8];
    float b4[4];
#pragma unroll
    for (int nt = 0; nt < 4; ++nt) b4[nt] = A4_b[nt * 16 + m];

    const f16x8 hz = {0, 0, 0, 0, 0, 0, 0, 0};

    // Sender row pointers (sender node index == seg)
    const unsigned short* ps1 = Q1 + (size_t)seg * (TT * HIDN) + m * 128 + kbase;
    const unsigned short* ps2 = Q2 + (size_t)seg * (TT * HIDN) + m * 128 + kbase;

    // ---- compute v_pre for this segment's edges, one edge per wave-iter ----
    for (int li = wv; li < S; li += 4) {
        int e = el_s[beg + li];
        int rn = b * NN + ri[e];

        f16x8 g[4];
        if (m < 12) {
            const unsigned short* pr1 = Q1 + (size_t)rn * (TT * HIDN) + m * 128 + kbase;
            const unsigned short* pr2 = Q2 + (size_t)rn * (TT * HIDN) + m * 128 + kbase;
            f16x8 s1[4], s2[4], r1[4], r2[4];
#pragma unroll
            for (int kt = 0; kt < 4; ++kt) {
                s1[kt] = *(const f16x8*)(ps1 + kt * 32);
                r2[kt] = *(const f16x8*)(pr2 + kt * 32);
                r1[kt] = *(const f16x8*)(pr1 + kt * 32);
                s2[kt] = *(const f16x8*)(ps2 + kt * 32);
            }
#pragma unroll
            for (int kt = 0; kt < 4; ++kt) {
                f16x8 a = s1[kt] + r2[kt];              // v_pk_add_f16
                f16x8 c = r1[kt] + s2[kt];
                g[kt] = __builtin_elementwise_max(a, hz)   // v_pk_max_f16
                      - __builtin_elementwise_max(c, hz);
            }
        } else {
#pragma unroll
            for (int kt = 0; kt < 4; ++kt) g[kt] = hz;
        }

        // Stage A3: Z = G @ A3 (K=128)
        f32x4 acc[4];
#pragma unroll
        for (int nt = 0; nt < 4; ++nt) acc[nt] = (f32x4){0.f, 0.f, 0.f, 0.f};
#pragma unroll
        for (int kt = 0; kt < 4; ++kt)
#pragma unroll
            for (int nt = 0; nt < 4; ++nt)
                acc[nt] = __builtin_amdgcn_mfma_f32_16x16x32_f16(g[kt], w3[kt][nt], acc[nt], 0, 0, 0);

        // relu -> wave-private f16 LDS tile (C layout in, A layout out)
#pragma unroll
        for (int nt = 0; nt < 4; ++nt)
#pragma unroll
            for (int r = 0; r < 4; ++r)
                Hs[wv][quad * 4 + r][nt * 16 + m] = (_Float16)fmaxf(acc[nt][r], 0.f);

        const _Float16* hp = &Hs[wv][m][kbase];
        f16x8 hf0 = *(const f16x8*)hp;            // ds_read_b128: 8 f16 = A-frag, no cvt
        f16x8 hf1 = *(const f16x8*)(hp + 32);

        // Stage A4: v_pre = H @ A4 + b4 (K=64)
#pragma unroll
        for (int nt = 0; nt < 4; ++nt) {
            f32x4 o = (f32x4){b4[nt], b4[nt], b4[nt], b4[nt]};
            o = __builtin_amdgcn_mfma_f32_16x16x32_f16(hf0, w4[0][nt], o, 0, 0, 0);
            o = __builtin_amdgcn_mfma_f32_16x16x32_f16(hf1, w4[1][nt], o, 0, 0, 0);
            if (quad < 3) {
                if (li < MAXSEG) {
#pragma unroll
                    for (int r = 0; r < 4; ++r)
                        Vseg[li][quad * 4 + r][nt * 16 + m] = f2h(o[r]);
                } else {            // rare overflow: spill fp32 v_pre to global
                    size_t ebase = (size_t)e * TD;
#pragma unroll
                    for (int r = 0; r < 4; ++r)
                        v[ebase + (quad * 4 + r) * 64 + nt * 16 + m] = o[r];
                }
            }
        }
    }
    __syncthreads();

    // ---- fused segment softmax: thread owns j = tid, tid+256, tid+512 ----
    int d  = tid & 63;
    int tb = tid >> 6;          // t for jj: tb + 4*jj
    int nL = min(S, MAXSEG);

    float mj[3] = {-1e30f, -1e30f, -1e30f};
    for (int i = 0; i < nL; ++i) {
#pragma unroll
        for (int jj = 0; jj < 3; ++jj)
            mj[jj] = fmaxf(mj[jj], h2f(Vseg[i][tb + 4 * jj][d]));
    }
    for (int i = MAXSEG; i < S; ++i) {
        size_t ebase = (size_t)el_s[beg + i] * TD;
#pragma unroll
        for (int jj = 0; jj < 3; ++jj)
            mj[jj] = fmaxf(mj[jj], v[ebase + (tb + 4 * jj) * 64 + d]);
    }

    float sj[3] = {0.f, 0.f, 0.f};
    for (int i = 0; i < nL; ++i) {
#pragma unroll
        for (int jj = 0; jj < 3; ++jj)
            sj[jj] += __expf(h2f(Vseg[i][tb + 4 * jj][d]) - mj[jj]);
    }
    for (int i = MAXSEG; i < S; ++i) {
        size_t ebase = (size_t)el_s[beg + i] * TD;
#pragma unroll
        for (int jj = 0; jj < 3; ++jj)
            sj[jj] += __expf(v[ebase + (tb + 4 * jj) * 64 + d] - mj[jj]);
    }

    float inv[3];
#pragma unroll
    for (int jj = 0; jj < 3; ++jj) inv[jj] = 1.f / (sj[jj] + 1e-12f);

    for (int i = 0; i < nL; ++i) {
        size_t ebase = (size_t)el_s[beg + i] * TD;
#pragma unroll
        for (int jj = 0; jj < 3; ++jj)
            v[ebase + (tb + 4 * jj) * 64 + d] =
                __expf(h2f(Vseg[i][tb + 4 * jj][d]) - mj[jj]) * inv[jj];
    }
    for (int i = MAXSEG; i < S; ++i) {
        size_t ebase = (size_t)el_s[beg + i] * TD;
#pragma unroll
        for (int jj = 0; jj < 3; ++jj) {
            size_t a = ebase + (tb + 4 * jj) * 64 + d;
            v[a] = __expf(v[a] - mj[jj]) * inv[jj];
        }
    }
}

// ---------------------------------------------------------------------------
// K4: per-node inbound aggregation + state update.
// ---------------------------------------------------------------------------
__global__ __launch_bounds__(256) void k_aggregate(const int* __restrict__ rp_r,
                                                   const int* __restrict__ el_r,
                                                   const int* __restrict__ si,
                                                   const float* __restrict__ x,
                                                   const float* __restrict__ v,
                                                   float* __restrict__ xout) {
    int node = blockIdx.x;
    int beg = rp_r[node], end = rp_r[node + 1];
    int tid = threadIdx.x;
    int b = node / NN;
    __shared__ int e_l[256];
    __shared__ int sb_l[256];
    float acc[3] = {0.f, 0.f, 0.f};
    for (int c = beg; c < end; c += 256) {
        int cnt = min(end - c, 256);
        if (tid < cnt) {
            int e = el_r[c + tid];
            e_l[tid] = e;
            sb_l[tid] = (b * NN + si[e]) * TD;
        }
        __syncthreads();
        for (int i = 0; i < cnt; ++i) {
            size_t vb = (size_t)e_l[i] * TD;
            int sb = sb_l[i];
#pragma unroll
            for (int jj = 0; jj < 3; ++jj) {
                int j = tid + jj * 256;
                acc[jj] += v[vb + j] * x[sb + j];
            }
        }
        __syncthreads();
    }
    size_t nb = (size_t)node * TD;
#pragma unroll
    for (int jj = 0; jj < 3; ++jj) {
        int j = tid + jj * 256;
        float xv = x[nb + j];
        xout[nb + j] = xv + STEPF * (acc[jj] - xv);
    }
}

// ---------------------------------------------------------------------------
extern "C" void kernel_launch(void* const* d_in, const int* in_sizes, int n_in,
                              void* d_out, int out_size, void* d_ws, size_t ws_size,
                              hipStream_t stream) {
    const float* x    = (const float*)d_in[0];
    const int*   bi   = (const int*)d_in[1];
    const int*   si   = (const int*)d_in[2];
    const int*   ri   = (const int*)d_in[3];
    const float* A1_w = (const float*)d_in[4];
    const float* A1_b = (const float*)d_in[5];
    const float* A2_w = (const float*)d_in[6];
    const float* A2_b = (const float*)d_in[7];
    const float* A3_w = (const float*)d_in[8];
    // d_in[9] = A3_b: cancels in z_ij - z_ji, unused
    const float* A4_w = (const float*)d_in[10];
    const float* A4_b = (const float*)d_in[11];

    float* xout = (float*)d_out;                          // [B,N,T,D]
    float* v    = (float*)d_out + (size_t)BN * TD;        // [E,T,D] final v_ij

    // Workspace: Q1,Q2 f16; W3f/W4f frag-packed f16 weights; CSR ints (~25 MB)
    unsigned short* Q1  = (unsigned short*)d_ws;
    unsigned short* Q2  = Q1 + (size_t)ROWS * HIDN;
    unsigned short* W3f = Q2 + (size_t)ROWS * HIDN;       // 8192
    unsigned short* W4f = W3f + 8192;                     // 4096
    int* cnt_s = (int*)(W4f + 4096);
    int* cnt_r = cnt_s + BN;
    int* rp_s  = cnt_r + BN;
    int* rp_r  = rp_s + BN + 1;
    int* cur_s = rp_r + BN + 1;
    int* cur_r = cur_s + BN;
    int* el_s  = cur_r + BN;
    int* el_r  = el_s + EE;

    k_zero<<<(2 * BN + 255) / 256, 256, 0, stream>>>(cnt_s, 2 * BN);
    k_count<<<EE / 256, 256, 0, stream>>>(bi, si, ri, cnt_s, cnt_r);
    k_scan<<<2, 256, 0, stream>>>(cnt_s, cnt_r, rp_s, rp_r, cur_s, cur_r);
    k_fill<<<EE / 256, 256, 0, stream>>>(bi, si, ri, cur_s, cur_r, el_s, el_r);
    k_prep_w<<<48, 256, 0, stream>>>(A3_w, A4_w, W3f, W4f);
    k_node_proj<<<ROWS / 16, 256, 0, stream>>>(x, A1_w, A1_b, A2_w, A2_b, Q1, Q2);
    k_edge_seg<<<BN, 256, 0, stream>>>(Q1, Q2, ri, rp_s, el_s, W3f, W4f, A4_b, v);
    k_aggregate<<<BN, 256, 0, stream>>>(rp_r, el_r, si, x, v, xout);
}

// Round 3
// 514.518 us; speedup vs baseline: 1.0369x; 1.0369x over previous
//
#include <hip/hip_runtime.h>
#include <math.h>

// Problem constants (from reference)
#define BB 4
#define NN 1000
#define TT 12
#define DD 64
#define HIDN 128
#define EFN 64
#define EE 64000
#define BN (BB*NN)        // 4000 segments
#define ROWS (BN*TT)      // 48000 node-time rows
#define TD (TT*DD)        // 768 elements per edge/node row-block
#define STEPF 0.1f
#define MAXSEG 22         // LDS-resident edges per sender segment (3 blocks/CU)
#define ELDS 48           // staged edge ids per block

typedef _Float16 f16x8 __attribute__((ext_vector_type(8)));   // 8 x f16 (4 VGPR)
typedef float f32x4 __attribute__((ext_vector_type(4)));      // MFMA acc

__device__ __forceinline__ unsigned short f2h(float x) {
    _Float16 h = (_Float16)x;                 // v_cvt_f16_f32 (RNE)
    return __builtin_bit_cast(unsigned short, h);
}
__device__ __forceinline__ float h2f(unsigned short u) {
    return (float)__builtin_bit_cast(_Float16, u);
}

// ---------------------------------------------------------------------------
// CSR build helpers
// ---------------------------------------------------------------------------
__global__ __launch_bounds__(256) void k_zero(int* __restrict__ p, int n) {
    int i = blockIdx.x * 256 + threadIdx.x;
    if (i < n) p[i] = 0;
}

__global__ __launch_bounds__(256) void k_count(const int* __restrict__ bi,
                                               const int* __restrict__ si,
                                               const int* __restrict__ ri,
                                               int* __restrict__ cnt_s,
                                               int* __restrict__ cnt_r) {
    int e = blockIdx.x * 256 + threadIdx.x;
    if (e < EE) {
        int b = bi[e];
        atomicAdd(&cnt_s[b * NN + si[e]], 1);
        atomicAdd(&cnt_r[b * NN + ri[e]], 1);
    }
}

__global__ __launch_bounds__(256) void k_scan(const int* __restrict__ cnt_s,
                                              const int* __restrict__ cnt_r,
                                              int* __restrict__ rp_s, int* __restrict__ rp_r,
                                              int* __restrict__ cur_s, int* __restrict__ cur_r) {
    const int* cnt = blockIdx.x ? cnt_r : cnt_s;
    int* rp  = blockIdx.x ? rp_r  : rp_s;
    int* cur = blockIdx.x ? cur_r : cur_s;
    __shared__ int part[256];
    int tid = threadIdx.x;
    const int chunk = 16;
    int bgn = tid * chunk;
    int end = min(bgn + chunk, BN);
    int s = 0;
    for (int i = bgn; i < end; ++i) s += cnt[i];
    part[tid] = s;
    __syncthreads();
    for (int off = 1; off < 256; off <<= 1) {
        int v = part[tid];
        if (tid >= off) v += part[tid - off];
        __syncthreads();
        part[tid] = v;
        __syncthreads();
    }
    int run = tid ? part[tid - 1] : 0;
    for (int i = bgn; i < end; ++i) { rp[i] = run; cur[i] = run; run += cnt[i]; }
    if (tid == 255) rp[BN] = part[255];
}

__global__ __launch_bounds__(256) void k_fill(const int* __restrict__ bi,
                                              const int* __restrict__ si,
                                              const int* __restrict__ ri,
                                              int* __restrict__ cur_s, int* __restrict__ cur_r,
                                              int* __restrict__ el_s, int* __restrict__ el_r) {
    int e = blockIdx.x * 256 + threadIdx.x;
    if (e < EE) {
        int b = bi[e];
        int ps = atomicAdd(&cur_s[b * NN + si[e]], 1);
        el_s[ps] = e;
        int pr = atomicAdd(&cur_r[b * NN + ri[e]], 1);
        el_r[pr] = e;
    }
}

// ---------------------------------------------------------------------------
// Weight prep: repack A3_w [128,64] and A4_w [64,64] into f16 MFMA B-fragment
// order for 16x16x32: frag[kt][nt][lane][j] = W[kt*32 + (lane>>4)*8 + j][nt*16 + (lane&15)]
// ---------------------------------------------------------------------------
__global__ __launch_bounds__(256) void k_prep_w(const float* __restrict__ A3_w,
                                                const float* __restrict__ A4_w,
                                                unsigned short* __restrict__ W3f,
                                                unsigned short* __restrict__ W4f) {
    int i = blockIdx.x * 256 + threadIdx.x;    // 0 .. 12287
    if (i < 8192) {
        int j = i & 7, lane = (i >> 3) & 63, nt = (i >> 9) & 3, kt = i >> 11;
        int k = kt * 32 + (lane >> 4) * 8 + j;
        int n = nt * 16 + (lane & 15);
        W3f[i] = f2h(A3_w[k * 64 + n]);
    } else if (i < 12288) {
        int ii = i - 8192;
        int j = ii & 7, lane = (ii >> 3) & 63, nt = (ii >> 9) & 3, kt = ii >> 11;
        int k = kt * 32 + (lane >> 4) * 8 + j;
        int n = nt * 16 + (lane & 15);
        W4f[ii] = f2h(A4_w[k * 64 + n]);
    }
}

// ---------------------------------------------------------------------------
// K1: node projections Q1 = x@A1_w + A1_b, Q2 = x@A2_w + A2_b -> f16
// ---------------------------------------------------------------------------
__global__ __launch_bounds__(256) void k_node_proj(const float* __restrict__ x,
                                                   const float* __restrict__ A1_w,
                                                   const float* __restrict__ A1_b,
                                                   const float* __restrict__ A2_w,
                                                   const float* __restrict__ A2_b,
                                                   unsigned short* __restrict__ Q1,
                                                   unsigned short* __restrict__ Q2) {
    __shared__ float xs[16][64];
    int tid = threadIdx.x;
    int row0 = blockIdx.x * 16;
    {
        int i = tid * 4;
        int r = i >> 6, k = i & 63;
        *(float4*)&xs[r][k] = *(const float4*)&x[(size_t)(row0 + r) * 64 + k];
    }
    __syncthreads();
    int h = tid & 127;
    int w = tid >> 7;
    const float* W = w ? A2_w : A1_w;
    float bias = w ? A2_b[h] : A1_b[h];
    float acc[16];
#pragma unroll
    for (int r = 0; r < 16; ++r) acc[r] = 0.f;
    for (int k = 0; k < 64; ++k) {
        float wv = W[k * 128 + h];
#pragma unroll
        for (int r = 0; r < 16; ++r) acc[r] += xs[r][k] * wv;
    }
    unsigned short* Qo = w ? Q2 : Q1;
    for (int r = 0; r < 16; ++r) Qo[(size_t)(row0 + r) * 128 + h] = f2h(acc[r] + bias);
}

// ---------------------------------------------------------------------------
// K2 (f16 MFMA + fused segment softmax): one workgroup per sender segment.
//  - w3 resident in VGPRs (64); w4 shared from LDS (8 KB) to stay under the
//    170-VGPR budget at 3 waves/EU (amdgpu_waves_per_eu(3,3) pins the tier —
//    round 1's allocator chased 6 waves/EU at 84 VGPRs and spilled weights).
//  - sender fragments hoisted to persistent regs (loop-invariant): halves the
//    per-edge global gather (6 KB instead of 12 KB).
//  - edge ids + receiver node ids staged to LDS at block start: the per-edge
//    dependent chain el_s[] -> ri[] -> Q-gather collapses to one LDS read.
//  - Vseg pitch 64 with quad-XOR column swizzle (col ^ (quad<<4)): store lanes
//    hit disjoint 8-bank groups per quad (conflict-free), saves 2.1 KB/edge.
// ---------------------------------------------------------------------------
__global__ __launch_bounds__(256) __attribute__((amdgpu_waves_per_eu(3, 3)))
void k_edge_seg(const unsigned short* __restrict__ Q1,
                const unsigned short* __restrict__ Q2,
                const int* __restrict__ ri,
                const int* __restrict__ rp_s,
                const int* __restrict__ el_s,
                const unsigned short* __restrict__ W3f,
                const unsigned short* __restrict__ W4f,
                const float* __restrict__ A4_b,
                float* __restrict__ v) {
    __shared__ unsigned short Vseg[MAXSEG][12][64];   // 33792 B, XOR-swizzled cols
    __shared__ __align__(16) _Float16 Hs[4][16][72];  // 9216 B (pitch 72: 16B-aligned b128 rows)
    __shared__ __align__(16) _Float16 W4s[4096];      // 8192 B, frag-packed A4 weights
    __shared__ int e_lds[ELDS];
    __shared__ int rn_lds[ELDS];

    int seg = blockIdx.x;
    int beg = rp_s[seg], end = rp_s[seg + 1];
    int S = end - beg;
    if (S == 0) return;

    int tid  = threadIdx.x;
    int lane = tid & 63;
    int wv   = tid >> 6;
    int quad = lane >> 4;
    int m    = lane & 15;
    int kbase = quad * 8;
    int b    = seg / NN;           // batch id (seg = b*NN + sender)

    // ---- block-start staging ----
    for (int i = tid; i < 512; i += 256)
        *(f16x8*)&W4s[i * 8] = *(const f16x8*)(const void*)&W4f[i * 8];
    if (tid < ELDS && tid < S) {
        int e = el_s[beg + tid];
        e_lds[tid] = e;
        rn_lds[tid] = b * NN + ri[e];
    }

    // w3 resident in registers (64 VGPR)
    f16x8 w3[4][4];
#pragma unroll
    for (int kt = 0; kt < 4; ++kt)
#pragma unroll
        for (int nt = 0; nt < 4; ++nt)
            w3[kt][nt] = *(const f16x8*)(const void*)&W3f[((kt * 4 + nt) * 64 + lane) * 8];
    float b4[4];
#pragma unroll
    for (int nt = 0; nt < 4; ++nt) b4[nt] = A4_b[nt * 16 + m];

    const f16x8 hz = {0, 0, 0, 0, 0, 0, 0, 0};

    // sender fragments: loop-invariant, persistent in regs (32 VGPR)
    f16x8 s1[4], s2[4];
    if (m < 12) {
        const unsigned short* p1 = Q1 + (size_t)seg * (TT * HIDN) + m * 128 + kbase;
        const unsigned short* p2 = Q2 + (size_t)seg * (TT * HIDN) + m * 128 + kbase;
#pragma unroll
        for (int kt = 0; kt < 4; ++kt) {
            s1[kt] = *(const f16x8*)(const void*)(p1 + kt * 32);
            s2[kt] = *(const f16x8*)(const void*)(p2 + kt * 32);
        }
    } else {
#pragma unroll
        for (int kt = 0; kt < 4; ++kt) { s1[kt] = hz; s2[kt] = hz; }
    }

    __syncthreads();

    // ---- compute v_pre for this segment's edges, one edge per wave-iter ----
    for (int li = wv; li < S; li += 4) {
        int e, rn;
        if (li < ELDS) { e = e_lds[li]; rn = rn_lds[li]; }
        else           { e = el_s[beg + li]; rn = b * NN + ri[e]; }

        const unsigned short* pr1 = Q1 + (size_t)rn * (TT * HIDN) + m * 128 + kbase;
        const unsigned short* pr2 = Q2 + (size_t)rn * (TT * HIDN) + m * 128 + kbase;

        // Stage A3: Z = G @ A3 (K=128), per-kt load->consume keeps pressure low
        f32x4 acc[4];
#pragma unroll
        for (int nt = 0; nt < 4; ++nt) acc[nt] = (f32x4){0.f, 0.f, 0.f, 0.f};
#pragma unroll
        for (int kt = 0; kt < 4; ++kt) {
            f16x8 g;
            if (m < 12) {
                f16x8 r1 = *(const f16x8*)(const void*)(pr1 + kt * 32);
                f16x8 r2 = *(const f16x8*)(const void*)(pr2 + kt * 32);
                f16x8 a = s1[kt] + r2;                    // v_pk_add_f16
                f16x8 c = r1 + s2[kt];
                g = __builtin_elementwise_max(a, hz)      // v_pk_max_f16
                  - __builtin_elementwise_max(c, hz);
            } else {
                g = hz;
            }
#pragma unroll
            for (int nt = 0; nt < 4; ++nt)
                acc[nt] = __builtin_amdgcn_mfma_f32_16x16x32_f16(g, w3[kt][nt], acc[nt], 0, 0, 0);
        }

        // relu -> wave-private f16 LDS tile (C layout in, A layout out)
#pragma unroll
        for (int nt = 0; nt < 4; ++nt)
#pragma unroll
            for (int r = 0; r < 4; ++r)
                Hs[wv][quad * 4 + r][nt * 16 + m] = (_Float16)fmaxf(acc[nt][r], 0.f);

        const _Float16* hp = &Hs[wv][m][kbase];
        f16x8 hf0 = *(const f16x8*)hp;            // ds_read_b128: 8 f16 = A-frag
        f16x8 hf1 = *(const f16x8*)(hp + 32);

        // Stage A4: v_pre = H @ A4 + b4 (K=64), w4 fragments from LDS
#pragma unroll
        for (int nt = 0; nt < 4; ++nt) {
            f32x4 o = (f32x4){b4[nt], b4[nt], b4[nt], b4[nt]};
            o = __builtin_amdgcn_mfma_f32_16x16x32_f16(hf0, *(const f16x8*)&W4s[(nt * 64 + lane) * 8], o, 0, 0, 0);
            o = __builtin_amdgcn_mfma_f32_16x16x32_f16(hf1, *(const f16x8*)&W4s[((4 + nt) * 64 + lane) * 8], o, 0, 0, 0);
            if (quad < 3) {
                if (li < MAXSEG) {
                    int cc = ((nt ^ quad) << 4) | m;      // swizzled column
#pragma unroll
                    for (int r = 0; r < 4; ++r)
                        Vseg[li][quad * 4 + r][cc] = f2h(o[r]);
                } else {            // rare overflow: spill fp32 v_pre to global
                    size_t ebase = (size_t)e * TD;
#pragma unroll
                    for (int r = 0; r < 4; ++r)
                        v[ebase + (quad * 4 + r) * 64 + nt * 16 + m] = o[r];
                }
            }
        }
    }
    __syncthreads();

    // ---- fused segment softmax: thread owns j = tid, tid+256, tid+512 ----
    int d  = tid & 63;
    int tb = tid >> 6;          // row for jj is tb + 4*jj; row>>2 == jj (tb<4)
    int nL = min(S, MAXSEG);
    int dd[3];
#pragma unroll
    for (int jj = 0; jj < 3; ++jj) dd[jj] = d ^ (jj << 4);   // un-swizzle

    float mj[3] = {-1e30f, -1e30f, -1e30f};
    for (int i = 0; i < nL; ++i) {
#pragma unroll
        for (int jj = 0; jj < 3; ++jj)
            mj[jj] = fmaxf(mj[jj], h2f(Vseg[i][tb + 4 * jj][dd[jj]]));
    }
    for (int i = MAXSEG; i < S; ++i) {
        int e = (i < ELDS) ? e_lds[i] : el_s[beg + i];
        size_t ebase = (size_t)e * TD;
#pragma unroll
        for (int jj = 0; jj < 3; ++jj)
            mj[jj] = fmaxf(mj[jj], v[ebase + (tb + 4 * jj) * 64 + d]);
    }

    float sj[3] = {0.f, 0.f, 0.f};
    for (int i = 0; i < nL; ++i) {
#pragma unroll
        for (int jj = 0; jj < 3; ++jj)
            sj[jj] += __expf(h2f(Vseg[i][tb + 4 * jj][dd[jj]]) - mj[jj]);
    }
    for (int i = MAXSEG; i < S; ++i) {
        int e = (i < ELDS) ? e_lds[i] : el_s[beg + i];
        size_t ebase = (size_t)e * TD;
#pragma unroll
        for (int jj = 0; jj < 3; ++jj)
            sj[jj] += __expf(v[ebase + (tb + 4 * jj) * 64 + d] - mj[jj]);
    }

    float inv[3];
#pragma unroll
    for (int jj = 0; jj < 3; ++jj) inv[jj] = 1.f / (sj[jj] + 1e-12f);

    for (int i = 0; i < nL; ++i) {
        int e = (i < ELDS) ? e_lds[i] : el_s[beg + i];
        size_t ebase = (size_t)e * TD;
#pragma unroll
        for (int jj = 0; jj < 3; ++jj)
            v[ebase + (tb + 4 * jj) * 64 + d] =
                __expf(h2f(Vseg[i][tb + 4 * jj][dd[jj]]) - mj[jj]) * inv[jj];
    }
    for (int i = MAXSEG; i < S; ++i) {
        int e = (i < ELDS) ? e_lds[i] : el_s[beg + i];
        size_t ebase = (size_t)e * TD;
#pragma unroll
        for (int jj = 0; jj < 3; ++jj) {
            size_t a = ebase + (tb + 4 * jj) * 64 + d;
            v[a] = __expf(v[a] - mj[jj]) * inv[jj];
        }
    }
}

// ---------------------------------------------------------------------------
// K4: per-node inbound aggregation + state update.
// ---------------------------------------------------------------------------
__global__ __launch_bounds__(256) void k_aggregate(const int* __restrict__ rp_r,
                                                   const int* __restrict__ el_r,
                                                   const int* __restrict__ si,
                                                   const float* __restrict__ x,
                                                   const float* __restrict__ v,
                                                   float* __restrict__ xout) {
    int node = blockIdx.x;
    int beg = rp_r[node], end = rp_r[node + 1];
    int tid = threadIdx.x;
    int b = node / NN;
    __shared__ int e_l[256];
    __shared__ int sb_l[256];
    float acc[3] = {0.f, 0.f, 0.f};
    for (int c = beg; c < end; c += 256) {
        int cnt = min(end - c, 256);
        if (tid < cnt) {
            int e = el_r[c + tid];
            e_l[tid] = e;
            sb_l[tid] = (b * NN + si[e]) * TD;
        }
        __syncthreads();
        for (int i = 0; i < cnt; ++i) {
            size_t vb = (size_t)e_l[i] * TD;
            int sb = sb_l[i];
#pragma unroll
            for (int jj = 0; jj < 3; ++jj) {
                int j = tid + jj * 256;
                acc[jj] += v[vb + j] * x[sb + j];
            }
        }
        __syncthreads();
    }
    size_t nb = (size_t)node * TD;
#pragma unroll
    for (int jj = 0; jj < 3; ++jj) {
        int j = tid + jj * 256;
        float xv = x[nb + j];
        xout[nb + j] = xv + STEPF * (acc[jj] - xv);
    }
}

// ---------------------------------------------------------------------------
extern "C" void kernel_launch(void* const* d_in, const int* in_sizes, int n_in,
                              void* d_out, int out_size, void* d_ws, size_t ws_size,
                              hipStream_t stream) {
    const float* x    = (const float*)d_in[0];
    const int*   bi   = (const int*)d_in[1];
    const int*   si   = (const int*)d_in[2];
    const int*   ri   = (const int*)d_in[3];
    const float* A1_w = (const float*)d_in[4];
    const float* A1_b = (const float*)d_in[5];
    const float* A2_w = (const float*)d_in[6];
    const float* A2_b = (const float*)d_in[7];
    const float* A3_w = (const float*)d_in[8];
    // d_in[9] = A3_b: cancels in z_ij - z_ji, unused
    const float* A4_w = (const float*)d_in[10];
    const float* A4_b = (const float*)d_in[11];

    float* xout = (float*)d_out;                          // [B,N,T,D]
    float* v    = (float*)d_out + (size_t)BN * TD;        // [E,T,D] final v_ij

    // Workspace: Q1,Q2 f16; W3f/W4f frag-packed f16 weights; CSR ints (~25 MB)
    unsigned short* Q1  = (unsigned short*)d_ws;
    unsigned short* Q2  = Q1 + (size_t)ROWS * HIDN;
    unsigned short* W3f = Q2 + (size_t)ROWS * HIDN;       // 8192
    unsigned short* W4f = W3f + 8192;                     // 4096
    int* cnt_s = (int*)(W4f + 4096);
    int* cnt_r = cnt_s + BN;
    int* rp_s  = cnt_r + BN;
    int* rp_r  = rp_s + BN + 1;
    int* cur_s = rp_r + BN + 1;
    int* cur_r = cur_s + BN;
    int* el_s  = cur_r + BN;
    int* el_r  = el_s + EE;

    k_zero<<<(2 * BN + 255) / 256, 256, 0, stream>>>(cnt_s, 2 * BN);
    k_count<<<EE / 256, 256, 0, stream>>>(bi, si, ri, cnt_s, cnt_r);
    k_scan<<<2, 256, 0, stream>>>(cnt_s, cnt_r, rp_s, rp_r, cur_s, cur_r);
    k_fill<<<EE / 256, 256, 0, stream>>>(bi, si, ri, cur_s, cur_r, el_s, el_r);
    k_prep_w<<<48, 256, 0, stream>>>(A3_w, A4_w, W3f, W4f);
    k_node_proj<<<ROWS / 16, 256, 0, stream>>>(x, A1_w, A1_b, A2_w, A2_b, Q1, Q2);
    k_edge_seg<<<BN, 256, 0, stream>>>(Q1, Q2, ri, rp_s, el_s, W3f, W4f, A4_b, v);
    k_aggregate<<<BN, 256, 0, stream>>>(rp_r, el_r, si, x, v, xout);
}

// Round 4
// 450.517 us; speedup vs baseline: 1.1842x; 1.1421x over previous
//
#include <hip/hip_runtime.h>
#include <math.h>

// Problem constants (from reference)
#define BB 4
#define NN 1000
#define TT 12
#define DD 64
#define HIDN 128
#define EFN 64
#define EE 64000
#define BN (BB*NN)        // 4000 segments
#define ROWS (BN*TT)      // 48000 node-time rows
#define TD (TT*DD)        // 768 elements per edge/node row-block
#define TD4 (TD/4)        // 192 float4 per row-block
#define STEPF 0.1f
#define MAXSEG 28         // LDS-resident edges per sender segment (2 blocks/CU)
#define ELDS 40           // staged edge ids per block

typedef _Float16 f16x8 __attribute__((ext_vector_type(8)));   // 8 x f16 (4 VGPR)
typedef float f32x4 __attribute__((ext_vector_type(4)));      // MFMA acc

__device__ __forceinline__ unsigned short f2h(float x) {
    _Float16 h = (_Float16)x;                 // v_cvt_f16_f32 (RNE)
    return __builtin_bit_cast(unsigned short, h);
}
__device__ __forceinline__ float h2f(unsigned short u) {
    return (float)__builtin_bit_cast(_Float16, u);
}

// ---------------------------------------------------------------------------
// CSR build helpers
// ---------------------------------------------------------------------------
__global__ __launch_bounds__(256) void k_zero(int* __restrict__ p, int n) {
    int i = blockIdx.x * 256 + threadIdx.x;
    if (i < n) p[i] = 0;
}

__global__ __launch_bounds__(256) void k_count(const int* __restrict__ bi,
                                               const int* __restrict__ si,
                                               const int* __restrict__ ri,
                                               int* __restrict__ cnt_s,
                                               int* __restrict__ cnt_r) {
    int e = blockIdx.x * 256 + threadIdx.x;
    if (e < EE) {
        int b = bi[e];
        atomicAdd(&cnt_s[b * NN + si[e]], 1);
        atomicAdd(&cnt_r[b * NN + ri[e]], 1);
    }
}

__global__ __launch_bounds__(256) void k_scan(const int* __restrict__ cnt_s,
                                              const int* __restrict__ cnt_r,
                                              int* __restrict__ rp_s, int* __restrict__ rp_r,
                                              int* __restrict__ cur_s, int* __restrict__ cur_r) {
    const int* cnt = blockIdx.x ? cnt_r : cnt_s;
    int* rp  = blockIdx.x ? rp_r  : rp_s;
    int* cur = blockIdx.x ? cur_r : cur_s;
    __shared__ int part[256];
    int tid = threadIdx.x;
    const int chunk = 16;
    int bgn = tid * chunk;
    int end = min(bgn + chunk, BN);
    int s = 0;
    for (int i = bgn; i < end; ++i) s += cnt[i];
    part[tid] = s;
    __syncthreads();
    for (int off = 1; off < 256; off <<= 1) {
        int v = part[tid];
        if (tid >= off) v += part[tid - off];
        __syncthreads();
        part[tid] = v;
        __syncthreads();
    }
    int run = tid ? part[tid - 1] : 0;
    for (int i = bgn; i < end; ++i) { rp[i] = run; cur[i] = run; run += cnt[i]; }
    if (tid == 255) rp[BN] = part[255];
}

__global__ __launch_bounds__(256) void k_fill(const int* __restrict__ bi,
                                              const int* __restrict__ si,
                                              const int* __restrict__ ri,
                                              int* __restrict__ cur_s, int* __restrict__ cur_r,
                                              int* __restrict__ el_s, int* __restrict__ el_r) {
    int e = blockIdx.x * 256 + threadIdx.x;
    if (e < EE) {
        int b = bi[e];
        int ps = atomicAdd(&cur_s[b * NN + si[e]], 1);
        el_s[ps] = e;
        int pr = atomicAdd(&cur_r[b * NN + ri[e]], 1);
        el_r[pr] = e;
    }
}

// ---------------------------------------------------------------------------
// Weight prep: repack A3_w [128,64] and A4_w [64,64] into f16 MFMA B-fragment
// order for 16x16x32: frag[kt][nt][lane][j] = W[kt*32 + (lane>>4)*8 + j][nt*16 + (lane&15)]
// ---------------------------------------------------------------------------
__global__ __launch_bounds__(256) void k_prep_w(const float* __restrict__ A3_w,
                                                const float* __restrict__ A4_w,
                                                unsigned short* __restrict__ W3f,
                                                unsigned short* __restrict__ W4f) {
    int i = blockIdx.x * 256 + threadIdx.x;    // 0 .. 12287
    if (i < 8192) {
        int j = i & 7, lane = (i >> 3) & 63, nt = (i >> 9) & 3, kt = i >> 11;
        int k = kt * 32 + (lane >> 4) * 8 + j;
        int n = nt * 16 + (lane & 15);
        W3f[i] = f2h(A3_w[k * 64 + n]);
    } else if (i < 12288) {
        int ii = i - 8192;
        int j = ii & 7, lane = (ii >> 3) & 63, nt = (ii >> 9) & 3, kt = ii >> 11;
        int k = kt * 32 + (lane >> 4) * 8 + j;
        int n = nt * 16 + (lane & 15);
        W4f[ii] = f2h(A4_w[k * 64 + n]);
    }
}

// ---------------------------------------------------------------------------
// K1: node projections Q1 = x@A1_w + A1_b, Q2 = x@A2_w + A2_b -> f16
// ---------------------------------------------------------------------------
__global__ __launch_bounds__(256) void k_node_proj(const float* __restrict__ x,
                                                   const float* __restrict__ A1_w,
                                                   const float* __restrict__ A1_b,
                                                   const float* __restrict__ A2_w,
                                                   const float* __restrict__ A2_b,
                                                   unsigned short* __restrict__ Q1,
                                                   unsigned short* __restrict__ Q2) {
    __shared__ float xs[16][64];
    int tid = threadIdx.x;
    int row0 = blockIdx.x * 16;
    {
        int i = tid * 4;
        int r = i >> 6, k = i & 63;
        *(float4*)&xs[r][k] = *(const float4*)&x[(size_t)(row0 + r) * 64 + k];
    }
    __syncthreads();
    int h = tid & 127;
    int w = tid >> 7;
    const float* W = w ? A2_w : A1_w;
    float bias = w ? A2_b[h] : A1_b[h];
    float acc[16];
#pragma unroll
    for (int r = 0; r < 16; ++r) acc[r] = 0.f;
    for (int k = 0; k < 64; ++k) {
        float wv = W[k * 128 + h];
#pragma unroll
        for (int r = 0; r < 16; ++r) acc[r] += xs[r][k] * wv;
    }
    unsigned short* Qo = w ? Q2 : Q1;
    for (int r = 0; r < 16; ++r) Qo[(size_t)(row0 + r) * 128 + h] = f2h(acc[r] + bias);
}

// ---------------------------------------------------------------------------
// K2 (f16 MFMA + fused segment softmax): one workgroup per sender segment.
//  - NO occupancy hints: round 0 (no hint) allocated to demand (124 VGPR, no
//    spill traffic); every hinted round (1,3) collapsed to 84 VGPR + ~250 MB
//    of scratch traffic. Let the allocator breathe.
//  - 2 blocks/CU (LDS 60.8 KB): round 0 evidence — 3 blocks/CU in rounds 1-3
//    thrashed per-XCD L2 (receiver-gather hit rate 63% -> 6%).
//  - w3 resident in VGPRs (64); w4 shared from LDS; sender fragments hoisted
//    (loop-invariant, halves per-edge gather); edge/receiver ids staged.
// ---------------------------------------------------------------------------
__global__ __launch_bounds__(256)
void k_edge_seg(const unsigned short* __restrict__ Q1,
                const unsigned short* __restrict__ Q2,
                const int* __restrict__ ri,
                const int* __restrict__ rp_s,
                const int* __restrict__ el_s,
                const unsigned short* __restrict__ W3f,
                const unsigned short* __restrict__ W4f,
                const float* __restrict__ A4_b,
                float* __restrict__ v) {
    __shared__ unsigned short Vseg[MAXSEG][12][64];   // 43008 B, XOR-swizzled cols
    __shared__ __align__(16) _Float16 Hs[4][16][72];  // 9216 B (pitch 72: 16B-aligned b128 rows)
    __shared__ __align__(16) _Float16 W4s[4096];      // 8192 B, frag-packed A4 weights
    __shared__ int e_lds[ELDS];
    __shared__ int rn_lds[ELDS];

    int seg = blockIdx.x;
    int beg = rp_s[seg], end = rp_s[seg + 1];
    int S = end - beg;
    if (S == 0) return;

    int tid  = threadIdx.x;
    int lane = tid & 63;
    int wv   = tid >> 6;
    int quad = lane >> 4;
    int m    = lane & 15;
    int kbase = quad * 8;
    int b    = seg / NN;           // batch id (seg = b*NN + sender)

    // ---- block-start staging ----
    for (int i = tid; i < 512; i += 256)
        *(f16x8*)&W4s[i * 8] = *(const f16x8*)(const void*)&W4f[i * 8];
    if (tid < ELDS && tid < S) {
        int e = el_s[beg + tid];
        e_lds[tid] = e;
        rn_lds[tid] = b * NN + ri[e];
    }

    // w3 resident in registers (64 VGPR)
    f16x8 w3[4][4];
#pragma unroll
    for (int kt = 0; kt < 4; ++kt)
#pragma unroll
        for (int nt = 0; nt < 4; ++nt)
            w3[kt][nt] = *(const f16x8*)(const void*)&W3f[((kt * 4 + nt) * 64 + lane) * 8];
    float b4[4];
#pragma unroll
    for (int nt = 0; nt < 4; ++nt) b4[nt] = A4_b[nt * 16 + m];

    const f16x8 hz = {0, 0, 0, 0, 0, 0, 0, 0};

    // sender fragments: loop-invariant, persistent in regs (32 VGPR)
    f16x8 s1[4], s2[4];
    if (m < 12) {
        const unsigned short* p1 = Q1 + (size_t)seg * (TT * HIDN) + m * 128 + kbase;
        const unsigned short* p2 = Q2 + (size_t)seg * (TT * HIDN) + m * 128 + kbase;
#pragma unroll
        for (int kt = 0; kt < 4; ++kt) {
            s1[kt] = *(const f16x8*)(const void*)(p1 + kt * 32);
            s2[kt] = *(const f16x8*)(const void*)(p2 + kt * 32);
        }
    } else {
#pragma unroll
        for (int kt = 0; kt < 4; ++kt) { s1[kt] = hz; s2[kt] = hz; }
    }

    __syncthreads();

    // ---- compute v_pre for this segment's edges, one edge per wave-iter ----
    for (int li = wv; li < S; li += 4) {
        int e, rn;
        if (li < ELDS) { e = e_lds[li]; rn = rn_lds[li]; }
        else           { e = el_s[beg + li]; rn = b * NN + ri[e]; }

        const unsigned short* pr1 = Q1 + (size_t)rn * (TT * HIDN) + m * 128 + kbase;
        const unsigned short* pr2 = Q2 + (size_t)rn * (TT * HIDN) + m * 128 + kbase;

        // Stage A3: Z = G @ A3 (K=128), per-kt load->consume keeps pressure low
        f32x4 acc[4];
#pragma unroll
        for (int nt = 0; nt < 4; ++nt) acc[nt] = (f32x4){0.f, 0.f, 0.f, 0.f};
#pragma unroll
        for (int kt = 0; kt < 4; ++kt) {
            f16x8 g;
            if (m < 12) {
                f16x8 r1 = *(const f16x8*)(const void*)(pr1 + kt * 32);
                f16x8 r2 = *(const f16x8*)(const void*)(pr2 + kt * 32);
                f16x8 a = s1[kt] + r2;                    // v_pk_add_f16
                f16x8 c = r1 + s2[kt];
                g = __builtin_elementwise_max(a, hz)      // v_pk_max_f16
                  - __builtin_elementwise_max(c, hz);
            } else {
                g = hz;
            }
#pragma unroll
            for (int nt = 0; nt < 4; ++nt)
                acc[nt] = __builtin_amdgcn_mfma_f32_16x16x32_f16(g, w3[kt][nt], acc[nt], 0, 0, 0);
        }

        // relu -> wave-private f16 LDS tile (C layout in, A layout out)
#pragma unroll
        for (int nt = 0; nt < 4; ++nt)
#pragma unroll
            for (int r = 0; r < 4; ++r)
                Hs[wv][quad * 4 + r][nt * 16 + m] = (_Float16)fmaxf(acc[nt][r], 0.f);

        const _Float16* hp = &Hs[wv][m][kbase];
        f16x8 hf0 = *(const f16x8*)hp;            // ds_read_b128: 8 f16 = A-frag
        f16x8 hf1 = *(const f16x8*)(hp + 32);

        // Stage A4: v_pre = H @ A4 + b4 (K=64), w4 fragments from LDS
#pragma unroll
        for (int nt = 0; nt < 4; ++nt) {
            f32x4 o = (f32x4){b4[nt], b4[nt], b4[nt], b4[nt]};
            o = __builtin_amdgcn_mfma_f32_16x16x32_f16(hf0, *(const f16x8*)&W4s[(nt * 64 + lane) * 8], o, 0, 0, 0);
            o = __builtin_amdgcn_mfma_f32_16x16x32_f16(hf1, *(const f16x8*)&W4s[((4 + nt) * 64 + lane) * 8], o, 0, 0, 0);
            if (quad < 3) {
                if (li < MAXSEG) {
                    int cc = ((nt ^ quad) << 4) | m;      // swizzled column
#pragma unroll
                    for (int r = 0; r < 4; ++r)
                        Vseg[li][quad * 4 + r][cc] = f2h(o[r]);
                } else {            // rare overflow: spill fp32 v_pre to global
                    size_t ebase = (size_t)e * TD;
#pragma unroll
                    for (int r = 0; r < 4; ++r)
                        v[ebase + (quad * 4 + r) * 64 + nt * 16 + m] = o[r];
                }
            }
        }
    }
    __syncthreads();

    // ---- fused segment softmax: thread owns j = tid, tid+256, tid+512 ----
    int d  = tid & 63;
    int tb = tid >> 6;          // row for jj is tb + 4*jj; row>>2 == jj (tb<4)
    int nL = min(S, MAXSEG);
    int dd[3];
#pragma unroll
    for (int jj = 0; jj < 3; ++jj) dd[jj] = d ^ (jj << 4);   // un-swizzle

    float mj[3] = {-1e30f, -1e30f, -1e30f};
    for (int i = 0; i < nL; ++i) {
#pragma unroll
        for (int jj = 0; jj < 3; ++jj)
            mj[jj] = fmaxf(mj[jj], h2f(Vseg[i][tb + 4 * jj][dd[jj]]));
    }
    for (int i = MAXSEG; i < S; ++i) {
        int e = (i < ELDS) ? e_lds[i] : el_s[beg + i];
        size_t ebase = (size_t)e * TD;
#pragma unroll
        for (int jj = 0; jj < 3; ++jj)
            mj[jj] = fmaxf(mj[jj], v[ebase + (tb + 4 * jj) * 64 + d]);
    }

    float sj[3] = {0.f, 0.f, 0.f};
    for (int i = 0; i < nL; ++i) {
#pragma unroll
        for (int jj = 0; jj < 3; ++jj)
            sj[jj] += __expf(h2f(Vseg[i][tb + 4 * jj][dd[jj]]) - mj[jj]);
    }
    for (int i = MAXSEG; i < S; ++i) {
        int e = (i < ELDS) ? e_lds[i] : el_s[beg + i];
        size_t ebase = (size_t)e * TD;
#pragma unroll
        for (int jj = 0; jj < 3; ++jj)
            sj[jj] += __expf(v[ebase + (tb + 4 * jj) * 64 + d] - mj[jj]);
    }

    float inv[3];
#pragma unroll
    for (int jj = 0; jj < 3; ++jj) inv[jj] = 1.f / (sj[jj] + 1e-12f);

    for (int i = 0; i < nL; ++i) {
        int e = (i < ELDS) ? e_lds[i] : el_s[beg + i];
        size_t ebase = (size_t)e * TD;
#pragma unroll
        for (int jj = 0; jj < 3; ++jj)
            v[ebase + (tb + 4 * jj) * 64 + d] =
                __expf(h2f(Vseg[i][tb + 4 * jj][dd[jj]]) - mj[jj]) * inv[jj];
    }
    for (int i = MAXSEG; i < S; ++i) {
        int e = (i < ELDS) ? e_lds[i] : el_s[beg + i];
        size_t ebase = (size_t)e * TD;
#pragma unroll
        for (int jj = 0; jj < 3; ++jj) {
            size_t a = ebase + (tb + 4 * jj) * 64 + d;
            v[a] = __expf(v[a] - mj[jj]) * inv[jj];
        }
    }
}

// ---------------------------------------------------------------------------
// K4: per-node inbound aggregation + state update. 192 threads; each thread
// owns one float4 column chunk (TD = 768 = 192 x 4): dwordx4 loads, 4x fewer
// load instructions than the scalar version, same coalescing.
// ---------------------------------------------------------------------------
__global__ __launch_bounds__(192) void k_aggregate(const int* __restrict__ rp_r,
                                                   const int* __restrict__ el_r,
                                                   const int* __restrict__ si,
                                                   const float* __restrict__ x,
                                                   const float* __restrict__ v,
                                                   float* __restrict__ xout) {
    int node = blockIdx.x;
    int beg = rp_r[node], end = rp_r[node + 1];
    int tid = threadIdx.x;
    int b = node / NN;
    __shared__ int e_l[192];
    __shared__ int sb_l[192];
    const float4* v4 = (const float4*)v;
    const float4* x4 = (const float4*)x;
    float4 acc = {0.f, 0.f, 0.f, 0.f};
    for (int c = beg; c < end; c += 192) {
        int cnt = min(end - c, 192);
        if (tid < cnt) {
            int e = el_r[c + tid];
            e_l[tid] = e;
            sb_l[tid] = (b * NN + si[e]) * TD4;
        }
        __syncthreads();
        for (int i = 0; i < cnt; ++i) {
            float4 vv = v4[(size_t)e_l[i] * TD4 + tid];
            float4 xx = x4[(size_t)sb_l[i] + tid];
            acc.x += vv.x * xx.x;
            acc.y += vv.y * xx.y;
            acc.z += vv.z * xx.z;
            acc.w += vv.w * xx.w;
        }
        __syncthreads();
    }
    size_t nb = (size_t)node * TD4 + tid;
    float4 xv = x4[nb];
    float4 o;
    o.x = xv.x + STEPF * (acc.x - xv.x);
    o.y = xv.y + STEPF * (acc.y - xv.y);
    o.z = xv.z + STEPF * (acc.z - xv.z);
    o.w = xv.w + STEPF * (acc.w - xv.w);
    ((float4*)xout)[nb] = o;
}

// ---------------------------------------------------------------------------
extern "C" void kernel_launch(void* const* d_in, const int* in_sizes, int n_in,
                              void* d_out, int out_size, void* d_ws, size_t ws_size,
                              hipStream_t stream) {
    const float* x    = (const float*)d_in[0];
    const int*   bi   = (const int*)d_in[1];
    const int*   si   = (const int*)d_in[2];
    const int*   ri   = (const int*)d_in[3];
    const float* A1_w = (const float*)d_in[4];
    const float* A1_b = (const float*)d_in[5];
    const float* A2_w = (const float*)d_in[6];
    const float* A2_b = (const float*)d_in[7];
    const float* A3_w = (const float*)d_in[8];
    // d_in[9] = A3_b: cancels in z_ij - z_ji, unused
    const float* A4_w = (const float*)d_in[10];
    const float* A4_b = (const float*)d_in[11];

    float* xout = (float*)d_out;                          // [B,N,T,D]
    float* v    = (float*)d_out + (size_t)BN * TD;        // [E,T,D] final v_ij

    // Workspace: Q1,Q2 f16; W3f/W4f frag-packed f16 weights; CSR ints (~25 MB)
    unsigned short* Q1  = (unsigned short*)d_ws;
    unsigned short* Q2  = Q1 + (size_t)ROWS * HIDN;
    unsigned short* W3f = Q2 + (size_t)ROWS * HIDN;       // 8192
    unsigned short* W4f = W3f + 8192;                     // 4096
    int* cnt_s = (int*)(W4f + 4096);
    int* cnt_r = cnt_s + BN;
    int* rp_s  = cnt_r + BN;
    int* rp_r  = rp_s + BN + 1;
    int* cur_s = rp_r + BN + 1;
    int* cur_r = cur_s + BN;
    int* el_s  = cur_r + BN;
    int* el_r  = el_s + EE;

    k_zero<<<(2 * BN + 255) / 256, 256, 0, stream>>>(cnt_s, 2 * BN);
    k_count<<<EE / 256, 256, 0, stream>>>(bi, si, ri, cnt_s, cnt_r);
    k_scan<<<2, 256, 0, stream>>>(cnt_s, cnt_r, rp_s, rp_r, cur_s, cur_r);
    k_fill<<<EE / 256, 256, 0, stream>>>(bi, si, ri, cur_s, cur_r, el_s, el_r);
    k_prep_w<<<48, 256, 0, stream>>>(A3_w, A4_w, W3f, W4f);
    k_node_proj<<<ROWS / 16, 256, 0, stream>>>(x, A1_w, A1_b, A2_w, A2_b, Q1, Q2);
    k_edge_seg<<<BN, 256, 0, stream>>>(Q1, Q2, ri, rp_s, el_s, W3f, W4f, A4_b, v);
    k_aggregate<<<BN, 192, 0, stream>>>(rp_r, el_r, si, x, v, xout);
}